// Round 9
// baseline (321.831 us; speedup 1.0000x reference)
//
#include <hip/hip_runtime.h>
#include <cstddef>

typedef __attribute__((ext_vector_type(8))) short bf16x8;
typedef __attribute__((ext_vector_type(4))) float f32x4;

#define MFMA(a, b, c) __builtin_amdgcn_mfma_f32_16x16x32_bf16((a), (b), (c), 0, 0, 0)

// ---- cheap hi/lo split (R7-verified: absmax 3.05e-5) ----
static __device__ __forceinline__ unsigned hi_bits(float f) {
  unsigned u = __builtin_bit_cast(unsigned, f);
  return (u + 0x8000u) & 0xFFFF0000u;
}
static __device__ __forceinline__ float asf(unsigned u) {
  return __builtin_bit_cast(float, u);
}
static __device__ __forceinline__ unsigned pack_hi(unsigned a, unsigned b) {
  return __builtin_amdgcn_perm(b, a, 0x07060302u);   // lo16=a>>16, hi16=b>>16
}
// RNE round (weight prep only)
static __device__ __forceinline__ unsigned short f2bf(float f) {
  unsigned u = __builtin_bit_cast(unsigned, f);
  u = u + 0x7FFFu + ((u >> 16) & 1u);
  return (unsigned short)(u >> 16);
}
static __device__ __forceinline__ float bf2f(unsigned short h) {
  unsigned u = ((unsigned)h) << 16;
  return __builtin_bit_cast(float, u);
}
static __device__ __forceinline__ float fast_sig(float x) {
  return __builtin_amdgcn_rcpf(1.0f + __expf(-x));
}
static __device__ __forceinline__ float fast_tanh(float x) {
  return 2.0f * __builtin_amdgcn_rcpf(1.0f + __expf(-2.0f * x)) - 1.0f;
}

// LDS-only barrier (R5/R7-verified safe)
static __device__ __forceinline__ void lds_barrier() {
  asm volatile("s_waitcnt lgkmcnt(0)\n\ts_barrier" ::: "memory");
}

// Activation buffer: [16 rows][256 B = 128 bf16 k-slots], XOR-swizzled per row.
// Rows 0..7 = real batches; rows 8..15 stay zero/bounded-garbage (MFMA cols 8..15 unused).
static __device__ __forceinline__ bf16x8 aread(const char* base, int lane, int kc) {
  int b = lane & 15, g = lane >> 4;
  int off = (kc * 64 + g * 16) ^ ((b & 7) << 4);
  return *(const bf16x8*)(base + b * 256 + off);
}
static __device__ __forceinline__ void awrite32(char* base, int b, int k, unsigned v) {
  int off = (2 * k) ^ ((b & 7) << 4);
  *(unsigned*)(base + b * 256 + off) = v;
}
static __device__ __forceinline__ void awrite64(char* base, int b, int k, unsigned long long v) {
  int off = (2 * k) ^ ((b & 7) << 4);   // k multiple of 4 -> 8B-aligned, inside 16B swizzle unit
  *(unsigned long long*)(base + b * 256 + off) = v;
}

// 512 blocks x 256 thr (4 waves) x 8 batch -> 2 independent barrier domains per CU.
// Weights = A-operand (rows = ghat) in VGPRs (4 n-frags/wave); activations = B-operand
// (cols = batch) in LDS; in-register cell update. Encoder: 1 lds_barrier/step.
// Phase 2: lagged pipeline (latent t=i | decoder t=i-1 | projection t=i-2), 1 barrier/iter.
extern "C" __global__ __launch_bounds__(256, 2)
void lstm_ae_mfma8(const float* __restrict__ x,
                   const float* __restrict__ eWih, const float* __restrict__ eWhh, const float* __restrict__ eb,
                   const float* __restrict__ lWih, const float* __restrict__ lWhh, const float* __restrict__ lb,
                   const float* __restrict__ dWih, const float* __restrict__ dWhh, const float* __restrict__ db,
                   const float* __restrict__ oW,  const float* __restrict__ ob,
                   float* __restrict__ out)
{
  __shared__ __align__(16) char sAhi[2][4096];
  __shared__ __align__(16) char sAlo[2][4096];

  const int tid  = threadIdx.x;
  const int lane = tid & 63;
  const int w    = tid >> 6;        // wave 0..3
  const int c16  = lane & 15;
  const int p4   = lane >> 4;
  const int bbase = blockIdx.x * 8; // 8 batches per block

  // ---------- zero both buffers (256 thr x 2 iters x 16B = 8KB per plane) ----------
  {
    f32x4 z = {0.f, 0.f, 0.f, 0.f};
#pragma unroll
    for (int i = 0; i < 2; ++i) {
      *(f32x4*)(&sAhi[0][0] + tid * 16 + i * 4096) = z;
      *(f32x4*)(&sAlo[0][0] + tid * 16 + i * 4096) = z;
    }
  }

  // ---------- encoder weights: 4 n-frags. row tr=c16 -> (u = w*16+(tr>>2)*4+n, ga = tr&3)
  // k: 0..39 = x (chunks 0,1), 64..127 = h_enc slot 64+u (chunks 2,3)
  bf16x8 ewh[4][4], ewl[4][4];
  float ebias[4][4];
#pragma unroll
  for (int n = 0; n < 4; ++n) {
    int u = w * 16 + (c16 >> 2) * 4 + n;
    int ga = c16 & 3;
#pragma unroll
    for (int r = 0; r < 4; ++r) ebias[n][r] = eb[r * 64 + (w * 16 + p4 * 4 + n)];
#pragma unroll
    for (int kc = 0; kc < 4; ++kc) {
      bf16x8 hi, lo;
#pragma unroll
      for (int e = 0; e < 8; ++e) {
        int k = kc * 32 + p4 * 8 + e;
        float v = 0.f;
        if (k < 40)       v = eWih[(ga * 64 + u) * 40 + k];
        else if (k >= 64) v = eWhh[(ga * 64 + u) * 64 + (k - 64)];
        unsigned short hh = f2bf(v);
        hi[e] = (short)hh;
        lo[e] = (short)f2bf(v - bf2f(hh));
      }
      ewh[n][kc] = hi; ewl[n][kc] = lo;
    }
  }

  lds_barrier();  // zeros visible

  // ---------- stage x(0) into buf 0 (80 threads on waves 2-3) ----------
  const bool stager = (tid >= 176);
  const int s0 = tid - 176;
  const int sb = s0 / 10, sf4 = s0 - (s0 / 10) * 10;
  if (stager) {
    f32x4 ld = *(const f32x4*)(x + ((size_t)(bbase + sb) * 100 + 0) * 40 + sf4 * 4);
    unsigned xh[4], xl[4];
#pragma unroll
    for (int e = 0; e < 4; ++e) {
      xh[e] = hi_bits(ld[e]);
      xl[e] = __builtin_bit_cast(unsigned, ld[e] - asf(xh[e]));
    }
    unsigned long long ph = (unsigned long long)pack_hi(xh[0], xh[1])
                          | ((unsigned long long)pack_hi(xh[2], xh[3]) << 32);
    unsigned long long pl = (unsigned long long)pack_hi(xl[0], xl[1])
                          | ((unsigned long long)pack_hi(xl[2], xl[3]) << 32);
    int off = (sf4 * 8) ^ ((sb & 7) << 4);
    *(unsigned long long*)(sAhi[0] + sb * 256 + off) = ph;
    *(unsigned long long*)(sAlo[0] + sb * 256 + off) = pl;
  }

  float cE[4] = {0.f, 0.f, 0.f, 0.f};
  int q = 0;
  lds_barrier();

  // ================= PHASE 1: encoder, 1 lds_barrier/step =================
#pragma unroll 1
  for (int t = 0; t < 100; ++t) {
    f32x4 xld;
    if (stager) {
      int tn = (t + 1 < 100) ? t + 1 : 99;
      xld = *(const f32x4*)(x + ((size_t)(bbase + sb) * 100 + tn) * 40 + sf4 * 4);
    }

    f32x4 acc[4];
#pragma unroll
    for (int n = 0; n < 4; ++n)
      acc[n] = f32x4{ebias[n][0], ebias[n][1], ebias[n][2], ebias[n][3]};
    const char* Ah = sAhi[q];
    const char* Al = sAlo[q];
#pragma unroll
    for (int kc = 0; kc < 4; ++kc) {
      bf16x8 ah = aread(Ah, lane, kc);
      bf16x8 al = aread(Al, lane, kc);
#pragma unroll
      for (int n = 0; n < 4; ++n) {
        acc[n] = MFMA(ewh[n][kc], ah, acc[n]);
        acc[n] = MFMA(ewl[n][kc], ah, acc[n]);
        acc[n] = MFMA(ewh[n][kc], al, acc[n]);
      }
    }

    char* AhN = sAhi[q ^ 1];
    char* AlN = sAlo[q ^ 1];
    unsigned hhb[4], hlb[4];
#pragma unroll
    for (int n = 0; n < 4; ++n) {
      float ii = fast_sig(acc[n][0]), ff = fast_sig(acc[n][1]);
      float gg = fast_tanh(acc[n][2]), oo = fast_sig(acc[n][3]);
      cE[n] = ff * cE[n] + ii * gg;
      float hv = oo * fast_tanh(cE[n]);
      hhb[n] = hi_bits(hv);
      hlb[n] = __builtin_bit_cast(unsigned, hv - asf(hhb[n]));
    }
    {
      unsigned long long ph = (unsigned long long)pack_hi(hhb[0], hhb[1])
                            | ((unsigned long long)pack_hi(hhb[2], hhb[3]) << 32);
      unsigned long long pl = (unsigned long long)pack_hi(hlb[0], hlb[1])
                            | ((unsigned long long)pack_hi(hlb[2], hlb[3]) << 32);
      awrite64(AhN, c16, 64 + w * 16 + p4 * 4, ph);
      awrite64(AlN, c16, 64 + w * 16 + p4 * 4, pl);
    }

    if (stager) {
      unsigned xh[4], xl[4];
#pragma unroll
      for (int e = 0; e < 4; ++e) {
        xh[e] = hi_bits(xld[e]);
        xl[e] = __builtin_bit_cast(unsigned, xld[e] - asf(xh[e]));
      }
      unsigned long long ph = (unsigned long long)pack_hi(xh[0], xh[1])
                            | ((unsigned long long)pack_hi(xh[2], xh[3]) << 32);
      unsigned long long pl = (unsigned long long)pack_hi(xl[0], xl[1])
                            | ((unsigned long long)pack_hi(xl[2], xl[3]) << 32);
      int off = (sf4 * 8) ^ ((sb & 7) << 4);
      *(unsigned long long*)(AhN + sb * 256 + off) = ph;
      *(unsigned long long*)(AlN + sb * 256 + off) = pl;
    }
    lds_barrier();
    q ^= 1;
  }
  // h(99) in buf[q] chunks 2,3.

  // ================= xg_lat = lb + lWih @ h_enc_last (2 n-frags/wave) =================
  f32x4 xga[2];
  {
#pragma unroll
    for (int n = 0; n < 2; ++n) {
      int u = w * 8 + (c16 >> 2) * 2 + n;
      int ga = c16 & 3;
      int ul = w * 8 + p4 * 2 + n;
      xga[n] = f32x4{lb[ul], lb[32 + ul], lb[64 + ul], lb[96 + ul]};
#pragma unroll
      for (int kci = 0; kci < 2; ++kci) {
        bf16x8 hi, lo;
#pragma unroll
        for (int e = 0; e < 8; ++e) {
          float v = lWih[(ga * 32 + u) * 64 + kci * 32 + p4 * 8 + e];
          unsigned short hh = f2bf(v);
          hi[e] = (short)hh;
          lo[e] = (short)f2bf(v - bf2f(hh));
        }
        bf16x8 ah = aread(sAhi[q], lane, 2 + kci);
        bf16x8 al = aread(sAlo[q], lane, 2 + kci);
        xga[n] = MFMA(hi, ah, xga[n]);
        xga[n] = MFMA(lo, ah, xga[n]);
        xga[n] = MFMA(hi, al, xga[n]);
      }
    }
  }
  lds_barrier();  // h_enc reads complete before re-zero

  // re-zero both buffers
  {
    f32x4 z = {0.f, 0.f, 0.f, 0.f};
#pragma unroll
    for (int i = 0; i < 2; ++i) {
      *(f32x4*)(&sAhi[0][0] + tid * 16 + i * 4096) = z;
      *(f32x4*)(&sAlo[0][0] + tid * 16 + i * 4096) = z;
    }
  }

  // ---------- phase-2 weights ----------
  // latent Whh: 2 n-frags, u = w*8+(tr>>2)*2+n, k 0..31 = h_lat slot u
  bf16x8 lwh[2], lwl[2];
#pragma unroll
  for (int n = 0; n < 2; ++n) {
    int u = w * 8 + (c16 >> 2) * 2 + n;
    int ga = c16 & 3;
    bf16x8 hi, lo;
#pragma unroll
    for (int e = 0; e < 8; ++e) {
      float v = lWhh[(ga * 32 + u) * 32 + p4 * 8 + e];
      unsigned short hh = f2bf(v);
      hi[e] = (short)hh;
      lo[e] = (short)f2bf(v - bf2f(hh));
    }
    lwh[n] = hi; lwl[n] = lo;
  }
  // decoder: 4 n-frags, u = w*16+(tr>>2)*4+n; k: 0..31 h_lat (Wih), 32..95 h_dec (Whh)
  bf16x8 dwh[4][3], dwl[4][3];
  float dbias[4][4];
#pragma unroll
  for (int n = 0; n < 4; ++n) {
    int u = w * 16 + (c16 >> 2) * 4 + n;
    int ga = c16 & 3;
#pragma unroll
    for (int r = 0; r < 4; ++r) dbias[n][r] = db[r * 64 + (w * 16 + p4 * 4 + n)];
#pragma unroll
    for (int kc = 0; kc < 3; ++kc) {
      bf16x8 hi, lo;
#pragma unroll
      for (int e = 0; e < 8; ++e) {
        int k = kc * 32 + p4 * 8 + e;
        float v = (k < 32) ? dWih[(ga * 64 + u) * 32 + k]
                           : dWhh[(ga * 64 + u) * 64 + (k - 32)];
        unsigned short hh = f2bf(v);
        hi[e] = (short)hh;
        lo[e] = (short)f2bf(v - bf2f(hh));
      }
      dwh[n][kc] = hi; dwl[n][kc] = lo;
    }
  }
  // projection (waves 0..2): rows = feature f = w*16 + c16; k chunks 1,2 = h_dec
  bf16x8 pwh[2], pwl[2];
  float pbias[4];
#pragma unroll
  for (int r = 0; r < 4; ++r) {
    int f = w * 16 + p4 * 4 + r;
    pbias[r] = (w < 3 && f < 40) ? ob[f] : 0.0f;
  }
  if (w < 3) {
    int f = w * 16 + c16;
#pragma unroll
    for (int kci = 0; kci < 2; ++kci) {
      bf16x8 hi, lo;
#pragma unroll
      for (int e = 0; e < 8; ++e) {
        float v = (f < 40) ? oW[f * 64 + kci * 32 + p4 * 8 + e] : 0.0f;
        unsigned short hh = f2bf(v);
        hi[e] = (short)hh;
        lo[e] = (short)f2bf(v - bf2f(hh));
      }
      pwh[kci] = hi; pwl[kci] = lo;
    }
  }

  float cL[2] = {0.f, 0.f};
  float cD[4] = {0.f, 0.f, 0.f, 0.f};
  lds_barrier();

  // ================= PHASE 2: lagged pipeline, 1 lds_barrier/iter =================
  // iter i: latent t=i | decoder t=i-1 | projection t=i-2.
  // h_lat(t) -> buf[t&1] k 0..31; h_dec(t) -> buf[t&1] k 32..95.
#pragma unroll 1
  for (int i = 0; i < 102; ++i) {
    const int pa = i & 1;
    bf16x8 c0h = aread(sAhi[pa ^ 1], lane, 0), c0l = aread(sAlo[pa ^ 1], lane, 0);
    bf16x8 d1h = aread(sAhi[pa], lane, 1),     d1l = aread(sAlo[pa], lane, 1);
    bf16x8 d2h = aread(sAhi[pa], lane, 2),     d2l = aread(sAlo[pa], lane, 2);

    // --- latent step t=i (reads h_lat(i-1) = c0) ---
    if (i < 100) {
      unsigned hb[2], lbits[2];
#pragma unroll
      for (int n = 0; n < 2; ++n) {
        f32x4 lac = xga[n];
        lac = MFMA(lwh[n], c0h, lac);
        lac = MFMA(lwl[n], c0h, lac);
        lac = MFMA(lwh[n], c0l, lac);
        float ii = fast_sig(lac[0]), ff = fast_sig(lac[1]);
        float gg = fast_tanh(lac[2]), oo = fast_sig(lac[3]);
        cL[n] = ff * cL[n] + ii * gg;
        float hv = oo * fast_tanh(cL[n]);
        hb[n] = hi_bits(hv);
        lbits[n] = __builtin_bit_cast(unsigned, hv - asf(hb[n]));
      }
      awrite32(sAhi[pa], c16, w * 8 + p4 * 2, pack_hi(hb[0], hb[1]));
      awrite32(sAlo[pa], c16, w * 8 + p4 * 2, pack_hi(lbits[0], lbits[1]));
    }

    // --- decoder step t=i-1 (reads h_lat(i-1) = c0, h_dec(i-2) = d1,d2) ---
    if (i >= 1 && i < 101) {
      unsigned hhb[4], hlb[4];
#pragma unroll
      for (int n = 0; n < 4; ++n) {
        f32x4 dac = f32x4{dbias[n][0], dbias[n][1], dbias[n][2], dbias[n][3]};
        dac = MFMA(dwh[n][0], c0h, dac);
        dac = MFMA(dwl[n][0], c0h, dac);
        dac = MFMA(dwh[n][0], c0l, dac);
        dac = MFMA(dwh[n][1], d1h, dac);
        dac = MFMA(dwl[n][1], d1h, dac);
        dac = MFMA(dwh[n][1], d1l, dac);
        dac = MFMA(dwh[n][2], d2h, dac);
        dac = MFMA(dwl[n][2], d2h, dac);
        dac = MFMA(dwh[n][2], d2l, dac);
        float ii = fast_sig(dac[0]), ff = fast_sig(dac[1]);
        float gg = fast_tanh(dac[2]), oo = fast_sig(dac[3]);
        cD[n] = ff * cD[n] + ii * gg;
        float hv = oo * fast_tanh(cD[n]);
        hhb[n] = hi_bits(hv);
        hlb[n] = __builtin_bit_cast(unsigned, hv - asf(hhb[n]));
      }
      unsigned long long ph = (unsigned long long)pack_hi(hhb[0], hhb[1])
                            | ((unsigned long long)pack_hi(hhb[2], hhb[3]) << 32);
      unsigned long long pl = (unsigned long long)pack_hi(hlb[0], hlb[1])
                            | ((unsigned long long)pack_hi(hlb[2], hlb[3]) << 32);
      awrite64(sAhi[pa ^ 1], c16, 32 + w * 16 + p4 * 4, ph);
      awrite64(sAlo[pa ^ 1], c16, 32 + w * 16 + p4 * 4, pl);
    }

    // --- projection t=i-2 (waves 0..2; shares d1,d2 reads; only batches 0..7 stored) ---
    if (i >= 2 && w < 3) {
      f32x4 pac = f32x4{pbias[0], pbias[1], pbias[2], pbias[3]};
      pac = MFMA(pwh[0], d1h, pac);
      pac = MFMA(pwl[0], d1h, pac);
      pac = MFMA(pwh[0], d1l, pac);
      pac = MFMA(pwh[1], d2h, pac);
      pac = MFMA(pwl[1], d2h, pac);
      pac = MFMA(pwh[1], d2l, pac);
      if (c16 < 8) {
#pragma unroll
        for (int r = 0; r < 4; ++r) {
          int f = w * 16 + p4 * 4 + r;
          if (f < 40)
            out[((size_t)(bbase + c16) * 100 + (i - 2)) * 40 + f] = pac[r];
        }
      }
    }
    lds_barrier();
  }
}

extern "C" void kernel_launch(void* const* d_in, const int* in_sizes, int n_in,
                              void* d_out, int out_size, void* d_ws, size_t ws_size,
                              hipStream_t stream) {
  const float* x    = (const float*)d_in[0];
  const float* eWih = (const float*)d_in[1];
  const float* eWhh = (const float*)d_in[2];
  const float* eb   = (const float*)d_in[3];
  const float* lWih = (const float*)d_in[4];
  const float* lWhh = (const float*)d_in[5];
  const float* lb   = (const float*)d_in[6];
  const float* dWih = (const float*)d_in[7];
  const float* dWhh = (const float*)d_in[8];
  const float* db   = (const float*)d_in[9];
  const float* oW   = (const float*)d_in[10];
  const float* ob   = (const float*)d_in[11];
  float* out = (float*)d_out;

  lstm_ae_mfma8<<<512, 256, 0, stream>>>(x, eWih, eWhh, eb, lWih, lWhh, lb,
                                         dWih, dWhh, db, oW, ob, out);
}

// Round 10
// 158.988 us; speedup vs baseline: 2.0242x; 2.0242x over previous
//
#include <hip/hip_runtime.h>
#include <cstddef>

typedef _Float16 f16x8 __attribute__((ext_vector_type(8)));
typedef __attribute__((ext_vector_type(4))) float f32x4;

#define MFMA(a, b, c) __builtin_amdgcn_mfma_f32_16x16x32_f16((a), (b), (c), 0, 0, 0)

static constexpr float LO_SCALE = 2048.0f;        // 2^11: keeps weight-lo in fp16 normal range
static constexpr float LO_INV   = 1.0f / 2048.0f;

// f32 -> fp16 RNE (v_cvt_f16_f32), bits in low u16
static __device__ __forceinline__ unsigned f2h_bits(float f) {
  _Float16 h = (_Float16)f;
  return (unsigned)__builtin_bit_cast(unsigned short, h);
}
// (a & 0xFFFF) | (b << 16), 1 v_perm_b32
static __device__ __forceinline__ unsigned pack16(unsigned a, unsigned b) {
  return __builtin_amdgcn_perm(b, a, 0x05040100u);
}
// weight split: v ~= hi + lo * 2^-11, both fp16 normal-range
static __device__ __forceinline__ void wsplit(float v, _Float16& hi, _Float16& lo) {
  _Float16 h = (_Float16)v;
  hi = h;
  lo = (_Float16)((v - (float)h) * LO_SCALE);
}
static __device__ __forceinline__ float fast_sig(float x) {
  return __builtin_amdgcn_rcpf(1.0f + __expf(-x));
}
static __device__ __forceinline__ float fast_tanh(float x) {
  return 2.0f * __builtin_amdgcn_rcpf(1.0f + __expf(-2.0f * x)) - 1.0f;
}

// LDS-only barrier (R5/R7-verified): orders LDS ops, leaves vmcnt in flight
static __device__ __forceinline__ void lds_barrier() {
  asm volatile("s_waitcnt lgkmcnt(0)\n\ts_barrier" ::: "memory");
}

// Activation buffer: [16 batch rows][256 B = 128 fp16 k-slots], XOR-swizzled per row.
// B-fragment (cols = batch): lane holds col b=lane&15, k = kc*32 + (lane>>4)*8 + {0..7}.
static __device__ __forceinline__ f16x8 aread(const char* base, int lane, int kc) {
  int b = lane & 15, g = lane >> 4;
  int off = (kc * 64 + g * 16) ^ ((b & 7) << 4);
  return *(const f16x8*)(base + b * 256 + off);
}
static __device__ __forceinline__ void awrite16(char* base, int b, int k, unsigned short v) {
  int off = (2 * k) ^ ((b & 7) << 4);
  *(unsigned short*)(base + b * 256 + off) = v;
}
static __device__ __forceinline__ void awrite32(char* base, int b, int k, unsigned v) {
  int off = (2 * k) ^ ((b & 7) << 4);
  *(unsigned*)(base + b * 256 + off) = v;
}

// 8 waves, 16 batch/block, grid 256. fp16 scheme: weights = A-operand (rows = ghat) in VGPRs
// as hi + lo*2^-11 fp16 pairs; activations = single fp16 plane in LDS (B-operand, cols=batch).
// Per chunk: acc = MFMA(wh,a,acc); accL = MFMA(wl,a,accL); gates = acc + accL*2^-11.
// In-register cell update. Encoder: 1 lds_barrier/step. Phase 2: lagged pipeline
// (latent t=i | decoder t=i-1 | projection t=i-2), 1 lds_barrier/iter.
extern "C" __global__ __launch_bounds__(512, 2)
void lstm_ae_mfma9(const float* __restrict__ x,
                   const float* __restrict__ eWih, const float* __restrict__ eWhh, const float* __restrict__ eb,
                   const float* __restrict__ lWih, const float* __restrict__ lWhh, const float* __restrict__ lb,
                   const float* __restrict__ dWih, const float* __restrict__ dWhh, const float* __restrict__ db,
                   const float* __restrict__ oW,  const float* __restrict__ ob,
                   float* __restrict__ out)
{
  __shared__ __align__(16) char sA[2][4096];

  const int tid  = threadIdx.x;
  const int lane = tid & 63;
  const int w    = tid >> 6;        // wave 0..7
  const int c16  = lane & 15;       // batch
  const int p4   = lane >> 4;
  const int bbase = blockIdx.x * 16;

  // ---------- zero both buffers (512 x 16B = 8KB) ----------
  {
    f32x4 z = {0.f, 0.f, 0.f, 0.f};
    *(f32x4*)(&sA[0][0] + tid * 16) = z;
  }

  // ---------- encoder weights: rows tr=c16 -> (u = w*8+(tr>>2)*2+n, ga = tr&3) ----------
  // k: 0..39 = x (chunks 0,1), 64..127 = h_enc slot 64+u (chunks 2,3)
  f16x8 ewh[2][4], ewl[2][4];
  float ebias[2][4];
#pragma unroll
  for (int n = 0; n < 2; ++n) {
    int u = w * 8 + (c16 >> 2) * 2 + n;
    int ga = c16 & 3;
#pragma unroll
    for (int r = 0; r < 4; ++r) ebias[n][r] = eb[r * 64 + (w * 8 + p4 * 2 + n)];
#pragma unroll
    for (int kc = 0; kc < 4; ++kc) {
      f16x8 hi, lo;
#pragma unroll
      for (int e = 0; e < 8; ++e) {
        int k = kc * 32 + p4 * 8 + e;
        float v = 0.f;
        if (k < 40)       v = eWih[(ga * 64 + u) * 40 + k];
        else if (k >= 64) v = eWhh[(ga * 64 + u) * 64 + (k - 64)];
        _Float16 h, l;
        wsplit(v, h, l);
        hi[e] = h; lo[e] = l;
      }
      ewh[n][kc] = hi; ewl[n][kc] = lo;
    }
  }

  lds_barrier();  // zeros visible

  // ---------- stage x(0) into buf 0 (160 threads, 4 floats -> 8 B each) ----------
  const bool stager = (tid < 160);
  const int sb = tid / 10, sf4 = tid - (tid / 10) * 10;
  if (stager) {
    f32x4 ld = *(const f32x4*)(x + ((size_t)(bbase + sb) * 100 + 0) * 40 + sf4 * 4);
    unsigned long long pv =
        (unsigned long long)pack16(f2h_bits(ld[0]), f2h_bits(ld[1]))
      | ((unsigned long long)pack16(f2h_bits(ld[2]), f2h_bits(ld[3])) << 32);
    int off = (sf4 * 8) ^ ((sb & 7) << 4);
    *(unsigned long long*)(sA[0] + sb * 256 + off) = pv;
  }

  float cE[2] = {0.f, 0.f};
  int q = 0;
  lds_barrier();

  // ================= PHASE 1: encoder, 1 lds_barrier/step =================
#pragma unroll 1
  for (int t = 0; t < 100; ++t) {
    f32x4 xld;
    if (stager) {
      int tn = (t + 1 < 100) ? t + 1 : 99;
      xld = *(const f32x4*)(x + ((size_t)(bbase + sb) * 100 + tn) * 40 + sf4 * 4);
    }

    f32x4 acc[2], accL[2];
#pragma unroll
    for (int n = 0; n < 2; ++n) {
      acc[n]  = f32x4{ebias[n][0], ebias[n][1], ebias[n][2], ebias[n][3]};
      accL[n] = f32x4{0.f, 0.f, 0.f, 0.f};
    }
    const char* A = sA[q];
#pragma unroll
    for (int kc = 0; kc < 4; ++kc) {
      f16x8 a = aread(A, lane, kc);
#pragma unroll
      for (int n = 0; n < 2; ++n) {
        acc[n]  = MFMA(ewh[n][kc], a, acc[n]);
        accL[n] = MFMA(ewl[n][kc], a, accL[n]);
      }
    }

    char* AN = sA[q ^ 1];
    unsigned hb[2];
#pragma unroll
    for (int n = 0; n < 2; ++n) {
      f32x4 gv = acc[n] + accL[n] * LO_INV;
      float ii = fast_sig(gv[0]), ff = fast_sig(gv[1]);
      float gg = fast_tanh(gv[2]), oo = fast_sig(gv[3]);
      cE[n] = ff * cE[n] + ii * gg;
      float hv = oo * fast_tanh(cE[n]);
      hb[n] = f2h_bits(hv);
    }
    awrite32(AN, c16, 64 + w * 8 + p4 * 2, pack16(hb[0], hb[1]));

    if (stager) {
      unsigned long long pv =
          (unsigned long long)pack16(f2h_bits(xld[0]), f2h_bits(xld[1]))
        | ((unsigned long long)pack16(f2h_bits(xld[2]), f2h_bits(xld[3])) << 32);
      int off = (sf4 * 8) ^ ((sb & 7) << 4);
      *(unsigned long long*)(AN + sb * 256 + off) = pv;
    }
    lds_barrier();
    q ^= 1;
  }
  // h(99) in buf[q] chunks 2,3.

  // ================= xg_lat = lb + lWih @ h_enc_last =================
  f32x4 xga;
  {
    int u = w * 4 + (c16 >> 2), ga = c16 & 3;
    int ul = w * 4 + p4;
    xga = f32x4{lb[ul], lb[32 + ul], lb[64 + ul], lb[96 + ul]};
    f32x4 xgaL = {0.f, 0.f, 0.f, 0.f};
#pragma unroll
    for (int kci = 0; kci < 2; ++kci) {
      f16x8 hi, lo;
#pragma unroll
      for (int e = 0; e < 8; ++e) {
        float v = lWih[(ga * 32 + u) * 64 + kci * 32 + p4 * 8 + e];
        _Float16 h, l;
        wsplit(v, h, l);
        hi[e] = h; lo[e] = l;
      }
      f16x8 a = aread(sA[q], lane, 2 + kci);
      xga  = MFMA(hi, a, xga);
      xgaL = MFMA(lo, a, xgaL);
    }
    xga = xga + xgaL * LO_INV;
  }
  lds_barrier();  // h_enc reads complete before re-zero

  // re-zero both buffers (h_lat(-1) = h_dec(-1) = h_dec(-2) = 0)
  {
    f32x4 z = {0.f, 0.f, 0.f, 0.f};
    *(f32x4*)(&sA[0][0] + tid * 16) = z;
  }

  // ---------- phase-2 weights ----------
  f16x8 lwh, lwl;
  {
    int u = w * 4 + (c16 >> 2), ga = c16 & 3;
    f16x8 hi, lo;
#pragma unroll
    for (int e = 0; e < 8; ++e) {
      float v = lWhh[(ga * 32 + u) * 32 + p4 * 8 + e];
      _Float16 h, l;
      wsplit(v, h, l);
      hi[e] = h; lo[e] = l;
    }
    lwh = hi; lwl = lo;
  }
  f16x8 dwh[2][3], dwl[2][3];
  float dbias[2][4];
#pragma unroll
  for (int n = 0; n < 2; ++n) {
    int u = w * 8 + (c16 >> 2) * 2 + n;
    int ga = c16 & 3;
#pragma unroll
    for (int r = 0; r < 4; ++r) dbias[n][r] = db[r * 64 + (w * 8 + p4 * 2 + n)];
#pragma unroll
    for (int kc = 0; kc < 3; ++kc) {
      f16x8 hi, lo;
#pragma unroll
      for (int e = 0; e < 8; ++e) {
        int k = kc * 32 + p4 * 8 + e;
        float v = (k < 32) ? dWih[(ga * 64 + u) * 32 + k]
                           : dWhh[(ga * 64 + u) * 64 + (k - 32)];
        _Float16 h, l;
        wsplit(v, h, l);
        hi[e] = h; lo[e] = l;
      }
      dwh[n][kc] = hi; dwl[n][kc] = lo;
    }
  }
  f16x8 pwh[2], pwl[2];
  float pbias[4];
#pragma unroll
  for (int r = 0; r < 4; ++r) {
    int f = w * 16 + p4 * 4 + r;
    pbias[r] = (w < 3 && f < 40) ? ob[f] : 0.0f;
  }
  if (w < 3) {
    int f = w * 16 + c16;
#pragma unroll
    for (int kci = 0; kci < 2; ++kci) {
      f16x8 hi, lo;
#pragma unroll
      for (int e = 0; e < 8; ++e) {
        float v = (f < 40) ? oW[f * 64 + kci * 32 + p4 * 8 + e] : 0.0f;
        _Float16 h, l;
        wsplit(v, h, l);
        hi[e] = h; lo[e] = l;
      }
      pwh[kci] = hi; pwl[kci] = lo;
    }
  }

  float cL = 0.f;
  float cD[2] = {0.f, 0.f};
  lds_barrier();

  // ================= PHASE 2: lagged pipeline, 1 lds_barrier/iter =================
  // iter i: latent t=i | decoder t=i-1 | projection t=i-2.
  // h_lat(t) -> buf[t&1] k 0..31; h_dec(t) -> buf[t&1] k 32..95.
#pragma unroll 1
  for (int i = 0; i < 102; ++i) {
    const int pa = i & 1;
    f16x8 c0 = aread(sA[pa ^ 1], lane, 0);
    f16x8 d1 = aread(sA[pa], lane, 1);
    f16x8 d2 = aread(sA[pa], lane, 2);

    // --- latent step t=i (reads h_lat(i-1) = c0) ---
    if (i < 100) {
      f32x4 lac = xga, lacL = {0.f, 0.f, 0.f, 0.f};
      lac  = MFMA(lwh, c0, lac);
      lacL = MFMA(lwl, c0, lacL);
      f32x4 gv = lac + lacL * LO_INV;
      float ii = fast_sig(gv[0]), ff = fast_sig(gv[1]);
      float gg = fast_tanh(gv[2]), oo = fast_sig(gv[3]);
      cL = ff * cL + ii * gg;
      float hv = oo * fast_tanh(cL);
      awrite16(sA[pa], c16, w * 4 + p4, (unsigned short)f2h_bits(hv));
    }

    // --- decoder step t=i-1 (reads h_lat(i-1) = c0, h_dec(i-2) = d1,d2) ---
    if (i >= 1 && i < 101) {
      unsigned hb[2];
#pragma unroll
      for (int n = 0; n < 2; ++n) {
        f32x4 dac = f32x4{dbias[n][0], dbias[n][1], dbias[n][2], dbias[n][3]};
        f32x4 dacL = {0.f, 0.f, 0.f, 0.f};
        dac  = MFMA(dwh[n][0], c0, dac);
        dacL = MFMA(dwl[n][0], c0, dacL);
        dac  = MFMA(dwh[n][1], d1, dac);
        dacL = MFMA(dwl[n][1], d1, dacL);
        dac  = MFMA(dwh[n][2], d2, dac);
        dacL = MFMA(dwl[n][2], d2, dacL);
        f32x4 gv = dac + dacL * LO_INV;
        float ii = fast_sig(gv[0]), ff = fast_sig(gv[1]);
        float gg = fast_tanh(gv[2]), oo = fast_sig(gv[3]);
        cD[n] = ff * cD[n] + ii * gg;
        float hv = oo * fast_tanh(cD[n]);
        hb[n] = f2h_bits(hv);
      }
      awrite32(sA[pa ^ 1], c16, 32 + w * 8 + p4 * 2, pack16(hb[0], hb[1]));
    }

    // --- projection t=i-2 (reads h_dec(i-2) = d1,d2; shares the reads) ---
    if (i >= 2 && w < 3) {
      f32x4 pac = f32x4{pbias[0], pbias[1], pbias[2], pbias[3]};
      f32x4 pacL = {0.f, 0.f, 0.f, 0.f};
      pac  = MFMA(pwh[0], d1, pac);
      pacL = MFMA(pwl[0], d1, pacL);
      pac  = MFMA(pwh[1], d2, pac);
      pacL = MFMA(pwl[1], d2, pacL);
      f32x4 pv = pac + pacL * LO_INV;
#pragma unroll
      for (int r = 0; r < 4; ++r) {
        int f = w * 16 + p4 * 4 + r;
        if (f < 40)
          out[((size_t)(bbase + c16) * 100 + (i - 2)) * 40 + f] = pv[r];
      }
    }
    lds_barrier();
  }
}

extern "C" void kernel_launch(void* const* d_in, const int* in_sizes, int n_in,
                              void* d_out, int out_size, void* d_ws, size_t ws_size,
                              hipStream_t stream) {
  const float* x    = (const float*)d_in[0];
  const float* eWih = (const float*)d_in[1];
  const float* eWhh = (const float*)d_in[2];
  const float* eb   = (const float*)d_in[3];
  const float* lWih = (const float*)d_in[4];
  const float* lWhh = (const float*)d_in[5];
  const float* lb   = (const float*)d_in[6];
  const float* dWih = (const float*)d_in[7];
  const float* dWhh = (const float*)d_in[8];
  const float* db   = (const float*)d_in[9];
  const float* oW   = (const float*)d_in[10];
  const float* ob   = (const float*)d_in[11];
  float* out = (float*)d_out;

  lstm_ae_mfma9<<<256, 512, 0, stream>>>(x, eWih, eWhh, eb, lWih, lWhh, lb,
                                         dWih, dWhh, db, oW, ob, out);
}